// Round 5
// baseline (224.970 us; speedup 1.0000x reference)
//
#include <hip/hip_runtime.h>
#include <stdint.h>

#define NSEG 50
#define HID 128
#define KDIM 2144      // 64 + 2016 + 64 (original logical K)
#define KD2 2240       // 64 + 2112 (levy padded to 4-pair groups/row) + 64; 35*64
#define KD2B 4480      // row bytes fp16
#define NROW 20000     // 400 * 50
#define NROW_PAD 20224 // 79 * 256 (GEMM BM=256 M-tiles)
#define GATES 512
#define NSEQ 400
#define NGRP 528       // sum over rows i of ceil((63-i)/4)

typedef __attribute__((ext_vector_type(8))) _Float16 f16x8;
typedef __attribute__((ext_vector_type(4))) _Float16 f16x4;
typedef __attribute__((ext_vector_type(4))) float f32x4;
typedef __attribute__((ext_vector_type(4))) uint32_t u32x4;

#define GLB_SPACE __attribute__((address_space(1)))
#define LDS_SPACE __attribute__((address_space(3)))

__device__ __forceinline__ void g2lds16(const void* g, void* l) {
    __builtin_amdgcn_global_load_lds((const GLB_SPACE uint32_t*)g,
                                     (LDS_SPACE uint32_t*)l, 16, 0, 0);
}

// group-offset of row i in the 4-padded levy layout: goff(i) = 528 - f(63-i),
// f(n) = sum_{L=1..n} ceil(L/4) = (q+1)*(2q+t), n = 4q+t
__device__ __forceinline__ int goff528(int i) {
    int n = 63 - i;
    int q = n >> 2, t = n & 3;
    return NGRP - (q + 1) * (2 * q + t);
}
__device__ __forceinline__ int ifromg(int g) {
    int i = 63 - (int)sqrtf(8.0f * (float)(NGRP - g));
    if (i < 0) i = 0;
    if (i > 62) i = 62;
    while (i > 0 && goff528(i) > g) i--;
    while (goff528(i + 1) <= g) i++;
    return i;
}

// uv4 column permutation: stride-4 j across lanes -> consecutive banks
#define UVP(c) ((((c) & 3) << 4) | ((c) >> 2))

// ---------------- features (blocks 0..799) + fused weight-prep (blocks 800..863) --------
// dev_0 == 0, so S2 = (p1-p0)x(p2-p1) + (p2-p0)x(p3-p2)
__global__ __launch_bounds__(512) void feat_kernel(const float* __restrict__ x,
                                                   const float* __restrict__ Wih,
                                                   const float* __restrict__ Whh,
                                                   const float* __restrict__ bih,
                                                   const float* __restrict__ bhh,
                                                   _Float16* __restrict__ feat,
                                                   _Float16* __restrict__ wh,
                                                   _Float16* __restrict__ whh16,
                                                   float* __restrict__ bias) {
    int bid = blockIdx.x;
    int tid = threadIdx.x;

    __shared__ float pbuf[64 * 101];                // p[c][t*25+v], stride 101 (bank fix)
    __shared__ __align__(16) float4 uv4[25 * 64];   // (u1,u2,v1,v2) per (v, UVP(c))

    if (bid >= 800) {
        // ---- prep path: permuted-K cast of W_ih to fp16, W_hh cast, bias sum ----
        int* kmap = (int*)pbuf;                     // 2240 ints, aliased onto pbuf
        for (int k = tid; k < KD2; k += 512) {
            int orig;
            if (k < 64) {
                orig = k;                            // lvl1
            } else if (k < 64 + 4 * NGRP) {
                int g = (k - 64) >> 2, p = (k - 64) & 3;
                int i = ifromg(g);
                int j = i + 1 + 4 * (g - goff528(i)) + p;
                orig = (j < 64) ? (64 + 63 * i - (i * (i - 1)) / 2 + (j - i - 1)) : -1;
            } else {
                orig = 2080 + (k - (64 + 4 * NGRP)); // start
            }
            kmap[k] = orig;
        }
        __syncthreads();
        const int nwih = 512 * KD2;
        const int nwhh = 512 * HID;
        const int total = nwih + nwhh + 512;
        for (int idx = (bid - 800) * 512 + tid; idx < total; idx += 64 * 512) {
            if (idx < nwih) {
                int row = idx / KD2;
                int k = idx - row * KD2;
                int orig = kmap[k];
                wh[idx] = (orig >= 0) ? (_Float16)Wih[row * KDIM + orig] : (_Float16)0.0f;
            } else if (idx < nwih + nwhh) {
                int q = idx - nwih;
                whh16[q] = (_Float16)Whh[q];
            } else {
                int g = idx - nwih - nwhh;
                bias[g] = bih[g] + bhh[g];
            }
        }
        return;
    }

    int b = bid / NSEG;
    int s = bid - b * NSEG;

    // load: x[b][c][4s+t][v] -> 100 contiguous floats per c
    for (int i = tid; i < 6400; i += 512) {
        int c = i / 100;
        int r = i - c * 100;
        pbuf[c * 101 + r] = x[(((size_t)b * 64 + c) * 200 + 4 * s) * 25 + r];
    }
    __syncthreads();

    // derived vectors + lvl1/start features
    for (int i = tid; i < 1600; i += 512) {
        int v = i >> 6;
        int c = i & 63;
        float p0 = pbuf[c * 101 + v];
        float p1 = pbuf[c * 101 + 25 + v];
        float p2 = pbuf[c * 101 + 50 + v];
        float p3 = pbuf[c * 101 + 75 + v];
        uv4[v * 64 + UVP(c)] = make_float4(p1 - p0, p2 - p0, p2 - p1, p3 - p2);
        size_t m = ((size_t)(b * 25 + v)) * NSEG + s;
        feat[m * KD2 + c] = (_Float16)(p3 - p0);             // lvl1
        feat[m * KD2 + (64 + 4 * NGRP) + c] = (_Float16)p0;  // start
    }
    __syncthreads();

    // levy: 2112 (group, v-block) items; g contiguous across lanes so a wave's
    // 64 stores for one v are 512 B contiguous. v-blocks of 7/6/6/6 balance load.
    for (int idx = tid; idx < 4 * NGRP; idx += 512) {
        int vb = idx / NGRP;
        int g = idx - vb * NGRP;
        int i = ifromg(g);
        int t = g - goff528(i);
        int j0 = i + 1 + 4 * t;
        int k0 = 64 + 4 * g;
        float msk[4];
        int jc[4];
#pragma unroll
        for (int p = 0; p < 4; p++) {
            int j = j0 + p;
            msk[p] = (j < 64) ? 0.5f : 0.0f;
            jc[p] = (j < 64) ? UVP(j) : UVP(63);
        }
        int ip = UVP(i);
        int v0 = (vb == 0) ? 0 : 6 * vb + 1;
        int vn = (vb == 0) ? 7 : 6;
        for (int vv = 0; vv < vn; vv++) {
            int v = v0 + vv;
            const float4* rowv = &uv4[v * 64];
            float4 a = rowv[ip];
            f16x4 o;
#pragma unroll
            for (int p = 0; p < 4; p++) {
                float4 bb = rowv[jc[p]];
                float val = msk[p] * (a.x * bb.z - bb.x * a.z + a.y * bb.w - bb.y * a.w);
                o[p] = (_Float16)val;
            }
            size_t m = ((size_t)(b * 25 + v)) * NSEG + s;
            *(f16x4*)(feat + m * KD2 + k0) = o;
        }
    }
}

// ---------------- GEMM: xproj2[s][q][gate] = feat @ W_ih^T + bias (fp16 out) ------------
// v5: 256x256 tile, counted-vmcnt RING pipeline (m201/T3+T4 port).
// LDS = ring of 4 K-half buffers (each: A 256x64B + B 256x64B = 32 KB; 128 KiB total).
// Phase h (one K=32 slice, 70 total): issue stage of half h+3 (4 g2lds/wave) ->
// s_waitcnt vmcnt(12) (certifies half h only; halves h+1..h+3 stay in flight across
// the barrier) -> s_barrier -> ds_read frags -> 32 MFMA (setprio) -> s_barrier.
// Tail peels vmcnt 8/4/0. Buffer H[(h+3)&3] was last read at phase h-1, and its
// re-stage is issued after phase h-1's closing barrier -> no WAR race. "memory"
// fences at every boundary stop hipcc moving LDS ops across raw barriers (rule 18).
// Per-row XOR chunk swizzle (slot = chunk ^ ((row>>1)&3)) with matching pre-swizzled
// g2lds SOURCE (both-sides involution, rule 21) -> even 8-access/bank ds_read_b128.
__global__ __launch_bounds__(512, 2) void gemm_kernel(const _Float16* __restrict__ feat,
                                                      const _Float16* __restrict__ wh,
                                                      const float* __restrict__ bias,
                                                      _Float16* __restrict__ xproj2) {
    int bid = blockIdx.x;          // 0..157
    int mt = bid >> 1;
    int nb = bid & 1;
    int m0 = mt * 256;
    int n0 = nb * 256;
    int tid = threadIdx.x;         // 0..511
    int wave = tid >> 6;           // 0..7
    int lane = tid & 63;
    int quad = lane >> 4;
    int l15 = lane & 15;
    int wm = (wave >> 1) * 64;     // 0,64,128,192 (4 M-waves)
    int wn = (wave & 1) * 128;     // 0,128        (2 N-waves)

    __shared__ __align__(16) char lds[4][32768];   // ring of 4 K-half buffers

    const f32x4 z4 = {0.f, 0.f, 0.f, 0.f};
    f32x4 acc[4][8];
    for (int i = 0; i < 4; i++)
        for (int j = 0; j < 8; j++) acc[i][j] = z4;

    const char* featB = (const char*)feat;
    const char* whB = (const char*)wh;

    // staging: per half, 32 g2lds units of 1 KB (16 rows x 64 B). Wave w owns units
    // {w, w+8} of A and {w, w+8} of B. lane l stages row (l>>2), chunk-slot (l&3);
    // source chunk = slot ^ ((row>>1)&3) = (l&3) ^ ((l>>3)&3).
    int lr = lane >> 2;
    int csw = (((lane & 3) ^ ((lane >> 3) & 3)) << 4);
    const char* aU0 = featB + (size_t)(m0 + wave * 16 + lr) * KD2B + csw;
    const char* aU1 = featB + (size_t)(m0 + (wave + 8) * 16 + lr) * KD2B + csw;
    const char* bU0 = whB + (size_t)(n0 + wave * 16 + lr) * KD2B + csw;
    const char* bU1 = whB + (size_t)(n0 + (wave + 8) * 16 + lr) * KD2B + csw;
    int dA0 = wave * 1024;
    int dA1 = (wave + 8) * 1024;
    int dB0 = 16384 + wave * 1024;
    int dB1 = 16384 + (wave + 8) * 1024;

    // fragment-read swizzled chunk byte: slot = quad ^ ((l15>>1)&3)
    int frsw = ((quad ^ ((l15 >> 1) & 3)) << 4);

#define STAGE_HALF(h_) do {                                   \
        char* Hb = lds[(h_) & 3];                             \
        size_t kb = (size_t)(h_) * 64;                        \
        g2lds16(aU0 + kb, Hb + dA0);                          \
        g2lds16(aU1 + kb, Hb + dA1);                          \
        g2lds16(bU0 + kb, Hb + dB0);                          \
        g2lds16(bU1 + kb, Hb + dB1);                          \
    } while (0)

#define GPHASE(h_, VM, DO_STAGE) do {                                         \
        if (DO_STAGE) STAGE_HALF((h_) + 3);                                   \
        asm volatile("s_waitcnt vmcnt(" #VM ")" ::: "memory");                \
        __builtin_amdgcn_s_barrier();                                         \
        asm volatile("" ::: "memory");                                        \
        const char* Hc = lds[(h_) & 3];                                       \
        f16x8 af[4], bf[8];                                                   \
        for (int tt = 0; tt < 4; tt++)                                        \
            af[tt] = *(const f16x8*)(Hc + (wm + tt * 16 + l15) * 64 + frsw);  \
        for (int tt = 0; tt < 8; tt++)                                        \
            bf[tt] = *(const f16x8*)(Hc + 16384 + (wn + tt * 16 + l15) * 64 + frsw); \
        __builtin_amdgcn_s_setprio(1);                                        \
        for (int mtl = 0; mtl < 4; mtl++)                                     \
            for (int ntl = 0; ntl < 8; ntl++)                                 \
                acc[mtl][ntl] = __builtin_amdgcn_mfma_f32_16x16x32_f16(af[mtl], bf[ntl], acc[mtl][ntl], 0, 0, 0); \
        __builtin_amdgcn_s_setprio(0);                                        \
        asm volatile("" ::: "memory");                                        \
        __builtin_amdgcn_s_barrier();                                         \
    } while (0)

    // prologue: stage halves 0,1,2 (12 loads in flight per wave)
    STAGE_HALF(0);
    STAGE_HALF(1);
    STAGE_HALF(2);

    // 70 K-half phases; steady state keeps 12 loads (3 halves) in flight
    for (int h = 0; h < 67; h++) GPHASE(h, 12, true);
    GPHASE(67, 8, false);
    GPHASE(68, 4, false);
    GPHASE(69, 0, false);

#undef GPHASE
#undef STAGE_HALF

    __syncthreads();

    // epilogue: 2 passes of 128 rows; stage fp16 in LDS (row stride 260 hw) for
    // coalesced 512 B/row stores. Pass p handled by waves with wave>>2 == p.
    _Float16* ep = (_Float16*)lds;
    for (int p = 0; p < 2; p++) {
        if ((wave >> 2) == p) {
            for (int ntl = 0; ntl < 8; ntl++) {
                int nl = wn + ntl * 16 + l15;
                float bv = bias[n0 + nl];
                for (int mtl = 0; mtl < 4; mtl++)
                    for (int r = 0; r < 4; r++) {
                        int relm = wm - p * 128 + mtl * 16 + quad * 4 + r;  // 0..127
                        ep[relm * 260 + nl] = (_Float16)(acc[mtl][ntl][r] + bv);
                    }
            }
        }
        __syncthreads();
        for (int it = 0; it < 8; it++) {
            int rowp = it * 16 + (tid >> 5);
            int m = m0 + p * 128 + rowp;
            if (m < NROW) {
                unsigned q = (unsigned)m / 50u;
                unsigned s = (unsigned)m - q * 50u;
                const char* src = (const char*)ep + rowp * 520 + (tid & 31) * 16;
                char* dst = (char*)xproj2 + ((size_t)s * NSEQ + q) * 1024 + (size_t)n0 * 2 + (tid & 31) * 16;
                *(u32x4*)dst = *(const u32x4*)src;
            }
        }
        __syncthreads();
    }
}

// ---------------- LSTM: 100 blocks x 4 seqs x 8 waves; NO per-step global ops -----------
// 25 steps of xproj preloaded into LDS (104 KB), refilled once at midpoint; all h
// outputs buffered in LDS (51 KB) and written out coalesced at the end. Steady-state
// step = LDS + MFMA + VALU + barrier only (no vmcnt drain on the critical path).
// Wave w owns hid [w*16,w*16+16) for all 4 gates; A rows replicated h[row&3]; quad=seq.
__global__ __launch_bounds__(512, 2) void lstm_kernel(const _Float16* __restrict__ xproj2,
                                                      const _Float16* __restrict__ whh,
                                                      _Float16* __restrict__ hseq) {
    int bid = blockIdx.x;        // 0..99
    int tid = threadIdx.x;
    int wave = tid >> 6;         // 0..7
    int lane = tid & 63;
    int quad = lane >> 4;        // = this lane's seq
    int col = lane & 15;
    int hid = wave * 16 + col;   // this lane's hid

    __shared__ __align__(16) char xbuf[25 * 4 * 1040];       // 104,000 B, rows padded
    __shared__ __align__(16) _Float16 hst[NSEG * 4 * HID];   // 51,200 B, [s][seq][hid]
    __shared__ __align__(16) _Float16 hbuf[2][4 * 144];      // 2,304 B, stride 144

    // B-frags: bfrag[g][kq]; B[k][n] = whh[g*128 + hid][k]
    f16x8 bfrag[4][4];
    for (int g = 0; g < 4; g++) {
        int n = g * 128 + hid;
        for (int kq = 0; kq < 4; kq++)
            bfrag[g][kq] = *(const f16x8*)(whh + (size_t)n * HID + kq * 32 + quad * 8);
    }
    for (int i = tid; i < 2 * 4 * 144; i += 512) ((_Float16*)hbuf)[i] = (_Float16)0.0f;
    float cst = 0.0f;

    const char* xsrc = (const char*)xproj2;
    // preload steps 0..24 (100 rows of 1 KB), 12-13 g2lds per wave
    for (int r = wave; r < 100; r += 8)
        g2lds16(xsrc + ((size_t)((r >> 2) * NSEQ + bid * 4 + (r & 3))) * 1024 + lane * 16,
                xbuf + r * 1040);
    __syncthreads();

    const f32x4 z4 = {0.f, 0.f, 0.f, 0.f};
    for (int half = 0; half < 2; half++) {
        for (int ss = 0; ss < 25; ss++) {
            int s = half * 25 + ss;
            int cur = s & 1;
            int nxt = cur ^ 1;

            // A-frags: A[m][k] = h[m&3][k] (replicated rows)
            f16x8 afrag[4];
            for (int kq = 0; kq < 4; kq++)
                afrag[kq] = *(const f16x8*)(&hbuf[cur][(col & 3) * 144 + kq * 32 + quad * 8]);

            // x_proj gates from LDS: 4 scalar reads for (seq=quad, hid)
            float xp[4];
            for (int g = 0; g < 4; g++)
                xp[g] = (float)(*(const _Float16*)(xbuf + (ss * 4 + quad) * 1040 +
                               (g * 128 + hid) * 2));

            f32x4 acc[4];
            for (int g = 0; g < 4; g++) {
                acc[g] = z4;
                for (int kq = 0; kq < 4; kq++)
                    acc[g] = __builtin_amdgcn_mfma_f32_16x16x32_f16(afrag[kq], bfrag[g][kq], acc[g], 0, 0, 0);
            }

            // extract element [quad] of each gate vector (C row quad*4+r = seq r)
            float gv[4];
            for (int g = 0; g < 4; g++) {
                float lo = (quad & 1) ? acc[g][1] : acc[g][0];
                float hi = (quad & 1) ? acc[g][3] : acc[g][2];
                gv[g] = (quad & 2) ? hi : lo;
            }

            float ip = gv[0] + xp[0];
            float fp = gv[1] + xp[1];
            float gp = gv[2] + xp[2];
            float op = gv[3] + xp[3];
            float si = __fdividef(1.0f, 1.0f + __expf(-ip));
            float sf = __fdividef(1.0f, 1.0f + __expf(-fp));
            float so = __fdividef(1.0f, 1.0f + __expf(-op));
            float eg = __expf(-2.0f * gp);
            float tg = __fdividef(1.0f - eg, 1.0f + eg);
            cst = sf * cst + si * tg;
            float ec = __expf(-2.0f * cst);
            float tc = __fdividef(1.0f - ec, 1.0f + ec);
            float hv = so * tc;
            _Float16 hv16 = (_Float16)hv;
            hbuf[nxt][quad * 144 + hid] = hv16;
            hst[(s * 4 + quad) * 128 + hid] = hv16;
            __syncthreads();
        }
        if (half == 0) {
            // refill slots 0..24 with steps 25..49 (one-time vmcnt drain)
            for (int r = wave; r < 100; r += 8)
                g2lds16(xsrc + ((size_t)((25 + (r >> 2)) * NSEQ + bid * 4 + (r & 3))) * 1024 + lane * 16,
                        xbuf + r * 1040);
            __syncthreads();
        }
    }

    // coalesced writeout of all 50 steps: 3200 dwordx4
    const u32x4* src = (const u32x4*)hst;
    for (int i = tid; i < 3200; i += 512) {
        int s = i >> 6;            // 64 vec4 per step
        int rem = i & 63;
        int seq = rem >> 4;
        int seg = rem & 15;
        u32x4 v = src[i];
        *(u32x4*)((char*)hseq + ((size_t)(s * NSEQ + bid * 4 + seq)) * 256 + seg * 16) = v;
    }
}

// ---------------- transpose: out[b][hid][s][v] = hseq[s][b*25+v][hid] -------------------
__global__ __launch_bounds__(256) void tr_kernel(const _Float16* __restrict__ hseq,
                                                 float* __restrict__ out) {
    int bid = blockIdx.x;        // 0..799 = b*50+s
    int b = bid / NSEG;
    int s = bid - b * NSEG;
    int tid = threadIdx.x;

    __shared__ _Float16 buf[25 * 130];   // [v][hid], padded 128->130

    const uint32_t* src32 = (const uint32_t*)(hseq + ((size_t)s * NSEQ + b * 25) * HID);
    uint32_t* buf32 = (uint32_t*)buf;
    for (int i = tid; i < 1600; i += 256) {       // 25 rows x 64 dwords, contiguous read
        int v = i >> 6;
        int d = i & 63;
        buf32[v * 65 + d] = src32[i];
    }
    __syncthreads();
    for (int i = tid; i < 3200; i += 256) {
        int hid = i / 25;
        int v = i - hid * 25;
        out[(((size_t)b * 128 + hid) * NSEG + s) * 25 + v] = (float)buf[v * 130 + hid];
    }
}

extern "C" void kernel_launch(void* const* d_in, const int* in_sizes, int n_in,
                              void* d_out, int out_size, void* d_ws, size_t ws_size,
                              hipStream_t stream) {
    const float* x = (const float*)d_in[0];
    const float* Wih = (const float*)d_in[1];
    const float* Whh = (const float*)d_in[2];
    const float* bih = (const float*)d_in[3];
    const float* bhh = (const float*)d_in[4];
    float* out = (float*)d_out;

    char* ws = (char*)d_ws;
    size_t off = 0;
    _Float16* feat = (_Float16*)(ws + off);   off += (size_t)NROW_PAD * KD2 * 2;      // 90.6 MB
    _Float16* xproj2 = (_Float16*)(ws + off); off += (size_t)NSEG * NSEQ * GATES * 2; // 20.5 MB
    _Float16* hseq = (_Float16*)(ws + off);   off += (size_t)NSEG * NSEQ * HID * 2;   // 5.1 MB
    _Float16* wh = (_Float16*)(ws + off);     off += (size_t)512 * KD2 * 2;           // 2.3 MB
    _Float16* whh16 = (_Float16*)(ws + off);  off += (size_t)512 * HID * 2;
    float* bias = (float*)(ws + off);         off += 512 * 4;

    hipLaunchKernelGGL(feat_kernel, dim3(864), dim3(512), 0, stream,
                       x, Wih, Whh, bih, bhh, feat, wh, whh16, bias);
    hipLaunchKernelGGL(gemm_kernel, dim3(158), dim3(512), 0, stream, feat, wh, bias, xproj2);
    hipLaunchKernelGGL(lstm_kernel, dim3(100), dim3(512), 0, stream, xproj2, whh16, hseq);
    hipLaunchKernelGGL(tr_kernel, dim3(16 * NSEG), dim3(256), 0, stream, hseq, out);
}

// Round 6
// 213.086 us; speedup vs baseline: 1.0558x; 1.0558x over previous
//
#include <hip/hip_runtime.h>
#include <stdint.h>

#define NSEG 50
#define HID 128
#define KDIM 2144      // 64 + 2016 + 64 (original logical K)
#define KD2 2240       // 64 + 2112 (levy padded to 4-pair groups/row) + 64; 35*64
#define KD2B 4480      // row bytes fp16
#define NROW 20000     // 400 * 50
#define NROW_PAD 20000 // 250 * 80 (BM=80 tiles exactly; no pad rows)
#define GATES 512
#define NSEQ 400
#define NGRP 528       // sum over rows i of ceil((63-i)/4)

typedef __attribute__((ext_vector_type(8))) _Float16 f16x8;
typedef __attribute__((ext_vector_type(4))) _Float16 f16x4;
typedef __attribute__((ext_vector_type(4))) float f32x4;
typedef __attribute__((ext_vector_type(4))) uint32_t u32x4;

#define GLB_SPACE __attribute__((address_space(1)))
#define LDS_SPACE __attribute__((address_space(3)))

__device__ __forceinline__ void g2lds16(const void* g, void* l) {
    __builtin_amdgcn_global_load_lds((const GLB_SPACE uint32_t*)g,
                                     (LDS_SPACE uint32_t*)l, 16, 0, 0);
}

// group-offset of row i in the 4-padded levy layout: goff(i) = 528 - f(63-i),
// f(n) = sum_{L=1..n} ceil(L/4) = (q+1)*(2q+t), n = 4q+t
__device__ __forceinline__ int goff528(int i) {
    int n = 63 - i;
    int q = n >> 2, t = n & 3;
    return NGRP - (q + 1) * (2 * q + t);
}
__device__ __forceinline__ int ifromg(int g) {
    int i = 63 - (int)sqrtf(8.0f * (float)(NGRP - g));
    if (i < 0) i = 0;
    if (i > 62) i = 62;
    while (i > 0 && goff528(i) > g) i--;
    while (goff528(i + 1) <= g) i++;
    return i;
}

// uv4 column permutation: stride-4 j across lanes -> consecutive banks
#define UVP(c) ((((c) & 3) << 4) | ((c) >> 2))

// ---------------- features (blocks 0..799) + fused weight-prep (blocks 800..863) --------
// dev_0 == 0, so S2 = (p1-p0)x(p2-p1) + (p2-p0)x(p3-p2)
__global__ __launch_bounds__(512) void feat_kernel(const float* __restrict__ x,
                                                   const float* __restrict__ Wih,
                                                   const float* __restrict__ Whh,
                                                   const float* __restrict__ bih,
                                                   const float* __restrict__ bhh,
                                                   _Float16* __restrict__ feat,
                                                   _Float16* __restrict__ wh,
                                                   _Float16* __restrict__ whh16,
                                                   float* __restrict__ bias) {
    int bid = blockIdx.x;
    int tid = threadIdx.x;

    __shared__ float pbuf[64 * 101];                // p[c][t*25+v], stride 101 (bank fix)
    __shared__ __align__(16) float4 uv4[25 * 64];   // (u1,u2,v1,v2) per (v, UVP(c))

    if (bid >= 800) {
        // ---- prep path: permuted-K cast of W_ih to fp16, W_hh cast, bias sum ----
        int* kmap = (int*)pbuf;                     // 2240 ints, aliased onto pbuf
        for (int k = tid; k < KD2; k += 512) {
            int orig;
            if (k < 64) {
                orig = k;                            // lvl1
            } else if (k < 64 + 4 * NGRP) {
                int g = (k - 64) >> 2, p = (k - 64) & 3;
                int i = ifromg(g);
                int j = i + 1 + 4 * (g - goff528(i)) + p;
                orig = (j < 64) ? (64 + 63 * i - (i * (i - 1)) / 2 + (j - i - 1)) : -1;
            } else {
                orig = 2080 + (k - (64 + 4 * NGRP)); // start
            }
            kmap[k] = orig;
        }
        __syncthreads();
        const int nwih = 512 * KD2;
        const int nwhh = 512 * HID;
        const int total = nwih + nwhh + 512;
        for (int idx = (bid - 800) * 512 + tid; idx < total; idx += 64 * 512) {
            if (idx < nwih) {
                int row = idx / KD2;
                int k = idx - row * KD2;
                int orig = kmap[k];
                wh[idx] = (orig >= 0) ? (_Float16)Wih[row * KDIM + orig] : (_Float16)0.0f;
            } else if (idx < nwih + nwhh) {
                int q = idx - nwih;
                whh16[q] = (_Float16)Whh[q];
            } else {
                int g = idx - nwih - nwhh;
                bias[g] = bih[g] + bhh[g];
            }
        }
        return;
    }

    int b = bid / NSEG;
    int s = bid - b * NSEG;

    // load: x[b][c][4s+t][v] -> 100 contiguous floats per c
    for (int i = tid; i < 6400; i += 512) {
        int c = i / 100;
        int r = i - c * 100;
        pbuf[c * 101 + r] = x[(((size_t)b * 64 + c) * 200 + 4 * s) * 25 + r];
    }
    __syncthreads();

    // derived vectors + lvl1/start features
    for (int i = tid; i < 1600; i += 512) {
        int v = i >> 6;
        int c = i & 63;
        float p0 = pbuf[c * 101 + v];
        float p1 = pbuf[c * 101 + 25 + v];
        float p2 = pbuf[c * 101 + 50 + v];
        float p3 = pbuf[c * 101 + 75 + v];
        uv4[v * 64 + UVP(c)] = make_float4(p1 - p0, p2 - p0, p2 - p1, p3 - p2);
        size_t m = ((size_t)(b * 25 + v)) * NSEG + s;
        feat[m * KD2 + c] = (_Float16)(p3 - p0);             // lvl1
        feat[m * KD2 + (64 + 4 * NGRP) + c] = (_Float16)p0;  // start
    }
    __syncthreads();

    // levy: 2112 (group, v-block) items; g contiguous across lanes so a wave's
    // 64 stores for one v are 512 B contiguous. v-blocks of 7/6/6/6 balance load.
    for (int idx = tid; idx < 4 * NGRP; idx += 512) {
        int vb = idx / NGRP;
        int g = idx - vb * NGRP;
        int i = ifromg(g);
        int t = g - goff528(i);
        int j0 = i + 1 + 4 * t;
        int k0 = 64 + 4 * g;
        float msk[4];
        int jc[4];
#pragma unroll
        for (int p = 0; p < 4; p++) {
            int j = j0 + p;
            msk[p] = (j < 64) ? 0.5f : 0.0f;
            jc[p] = (j < 64) ? UVP(j) : UVP(63);
        }
        int ip = UVP(i);
        int v0 = (vb == 0) ? 0 : 6 * vb + 1;
        int vn = (vb == 0) ? 7 : 6;
        for (int vv = 0; vv < vn; vv++) {
            int v = v0 + vv;
            const float4* rowv = &uv4[v * 64];
            float4 a = rowv[ip];
            f16x4 o;
#pragma unroll
            for (int p = 0; p < 4; p++) {
                float4 bb = rowv[jc[p]];
                float val = msk[p] * (a.x * bb.z - bb.x * a.z + a.y * bb.w - bb.y * a.w);
                o[p] = (_Float16)val;
            }
            size_t m = ((size_t)(b * 25 + v)) * NSEG + s;
            *(f16x4*)(feat + m * KD2 + k0) = o;
        }
    }
}

// ---------------- GEMM: xproj2[s][q][gate] = feat @ W_ih^T + bias (fp16 out) ------------
// v6: SINGLE-WAVE barrier-free blocks. BM=80 x BN=128 per wave (acc[5][8], ~230 VGPR,
// 1 wave/SIMD); grid 1000 = 250 M-tiles x 4 N-tiles = 4 blocks/CU on 250 CUs
// (20000 = 250*80 exactly -> zero pad FLOPs; MFMA floor 25 us).
// Model (R1-R5 post-mortem, corrected per-CU MFMA rate 3.38 KFLOP/cyc): all prior
// schedules were LDS-traffic + coverage bound. This geometry: frag reads 13 KB per
// 0.92 MFLOP (14 B/KFLOP) -> MFMA-bound. ZERO barriers: each wave self-paces on its
// own ring-2 LDS (26.6 KB) with counted vmcnt(13); the only hazards are intra-wave
// (vmcnt certifies slice h before read; lgkmcnt(0) fences frag reads before the
// same-buffer re-stage). Inter-wave races structurally impossible.
__global__ __launch_bounds__(64, 1) void gemm_kernel(const _Float16* __restrict__ feat,
                                                     const _Float16* __restrict__ wh,
                                                     const float* __restrict__ bias,
                                                     _Float16* __restrict__ xproj2) {
    int bid = blockIdx.x;          // 0..999
    int xcd = bid & 7;
    int idx = bid >> 3;
    int wg = xcd * 125 + idx;      // 1000 = 8*125: bijective; in-XCD runs share A-panels
    int mt = wg >> 2;              // 0..249
    int nb = wg & 3;
    int m0 = mt * 80;
    int n0 = nb * 128;
    int lane = threadIdx.x;        // 0..63
    int quad = lane >> 4;
    int l15 = lane & 15;

    __shared__ __align__(16) char lds[2][13312];   // slice: A 80x64B (0) + B 128x64B (+5120)

    const f32x4 z4 = {0.f, 0.f, 0.f, 0.f};
    f32x4 acc[5][8];
#pragma unroll
    for (int i = 0; i < 5; i++)
#pragma unroll
        for (int j = 0; j < 8; j++) acc[i][j] = z4;

    // staging sources: unit u = 16 rows; lane l covers row (l>>2), 16-B chunk (l&3).
    // g2lds dest is wave-uniform base + lane*16 -> exactly the linear [row][chunk] layout.
    int lr = lane >> 2;
    int lc = (lane & 3) * 16;
    const char* aS[5];
    const char* bS[8];
#pragma unroll
    for (int u = 0; u < 5; u++)
        aS[u] = (const char*)feat + (size_t)(m0 + u * 16 + lr) * KD2B + lc;
#pragma unroll
    for (int u = 0; u < 8; u++)
        bS[u] = (const char*)wh + (size_t)(n0 + u * 16 + lr) * KD2B + lc;

#define STAGE(h_) do {                                                        \
        char* Hb = lds[(h_) & 1];                                             \
        size_t kb = (size_t)(h_) * 64;                                        \
        for (int u = 0; u < 5; u++) g2lds16(aS[u] + kb, Hb + u * 1024);       \
        for (int u = 0; u < 8; u++) g2lds16(bS[u] + kb, Hb + 5120 + u * 1024);\
    } while (0)

// phase h = one K=32 slice (70 total). vmcnt(13) retires the oldest 13 loads =
// slice h (slice h+1's 13 stay in flight). lgkmcnt(0) before STAGE(h+2): the
// re-stage targets THIS phase's buffer (ring-2), so frag reads must be in regs.
#define GPHASE(h_, VMLIT, DO_STAGE) do {                                      \
        asm volatile("s_waitcnt vmcnt(" #VMLIT ")" ::: "memory");             \
        const char* Hc = lds[(h_) & 1];                                       \
        f16x8 af[5], bf[8];                                                   \
        for (int tt = 0; tt < 5; tt++)                                        \
            af[tt] = *(const f16x8*)(Hc + (tt * 16 + l15) * 64 + quad * 16);  \
        for (int tt = 0; tt < 8; tt++)                                        \
            bf[tt] = *(const f16x8*)(Hc + 5120 + (tt * 16 + l15) * 64 + quad * 16); \
        asm volatile("s_waitcnt lgkmcnt(0)" ::: "memory");                    \
        __builtin_amdgcn_sched_barrier(0);                                    \
        if (DO_STAGE) STAGE((h_) + 2);                                        \
        for (int mtl = 0; mtl < 5; mtl++)                                     \
            for (int ntl = 0; ntl < 8; ntl++)                                 \
                acc[mtl][ntl] = __builtin_amdgcn_mfma_f32_16x16x32_f16(af[mtl], bf[ntl], acc[mtl][ntl], 0, 0, 0); \
    } while (0)

    // prologue: slices 0 and 1 in flight (26 loads)
    STAGE(0);
    STAGE(1);

    for (int h = 0; h < 68; h++) GPHASE(h, 13, true);
    GPHASE(68, 13, false);
    GPHASE(69, 0, false);

#undef GPHASE
#undef STAGE

    // epilogue (single wave, no barriers): 5 passes of 16 rows through LDS
    // (stride 132 hw) -> coalesced 256-B row segments out.
    float bv[8];
#pragma unroll
    for (int ntl = 0; ntl < 8; ntl++) bv[ntl] = bias[n0 + ntl * 16 + l15];

    _Float16* ep = (_Float16*)lds;
    for (int p = 0; p < 5; p++) {
#pragma unroll
        for (int ntl = 0; ntl < 8; ntl++)
#pragma unroll
            for (int r = 0; r < 4; r++)
                ep[(quad * 4 + r) * 132 + ntl * 16 + l15] =
                    (_Float16)(acc[p][ntl][r] + bv[ntl]);
        asm volatile("s_waitcnt lgkmcnt(0)" ::: "memory");
#pragma unroll
        for (int t = 0; t < 4; t++) {
            int rr = t * 4 + quad;             // 0..15
            int m = m0 + p * 16 + rr;          // < 20000 always (exact tiling)
            unsigned q = (unsigned)m / 50u;
            unsigned s = (unsigned)m - q * 50u;
            const char* src = (const char*)ep + rr * 264 + l15 * 16;
            char* dst = (char*)xproj2 + ((size_t)s * NSEQ + q) * 1024 + (size_t)n0 * 2 + l15 * 16;
            *(u32x4*)dst = *(const u32x4*)src;
        }
        asm volatile("s_waitcnt lgkmcnt(0)" ::: "memory");  // reads done before next pass overwrites
    }
}

// ---------------- LSTM: 100 blocks x 4 seqs x 8 waves; NO per-step global ops -----------
// 25 steps of xproj preloaded into LDS (104 KB), refilled once at midpoint; all h
// outputs buffered in LDS (51 KB) and written out coalesced at the end. Steady-state
// step = LDS + MFMA + VALU + barrier only (no vmcnt drain on the critical path).
// Wave w owns hid [w*16,w*16+16) for all 4 gates; A rows replicated h[row&3]; quad=seq.
__global__ __launch_bounds__(512, 2) void lstm_kernel(const _Float16* __restrict__ xproj2,
                                                      const _Float16* __restrict__ whh,
                                                      _Float16* __restrict__ hseq) {
    int bid = blockIdx.x;        // 0..99
    int tid = threadIdx.x;
    int wave = tid >> 6;         // 0..7
    int lane = tid & 63;
    int quad = lane >> 4;        // = this lane's seq
    int col = lane & 15;
    int hid = wave * 16 + col;   // this lane's hid

    __shared__ __align__(16) char xbuf[25 * 4 * 1040];       // 104,000 B, rows padded
    __shared__ __align__(16) _Float16 hst[NSEG * 4 * HID];   // 51,200 B, [s][seq][hid]
    __shared__ __align__(16) _Float16 hbuf[2][4 * 144];      // 2,304 B, stride 144

    // B-frags: bfrag[g][kq]; B[k][n] = whh[g*128 + hid][k]
    f16x8 bfrag[4][4];
    for (int g = 0; g < 4; g++) {
        int n = g * 128 + hid;
        for (int kq = 0; kq < 4; kq++)
            bfrag[g][kq] = *(const f16x8*)(whh + (size_t)n * HID + kq * 32 + quad * 8);
    }
    for (int i = tid; i < 2 * 4 * 144; i += 512) ((_Float16*)hbuf)[i] = (_Float16)0.0f;
    float cst = 0.0f;

    const char* xsrc = (const char*)xproj2;
    // preload steps 0..24 (100 rows of 1 KB), 12-13 g2lds per wave
    for (int r = wave; r < 100; r += 8)
        g2lds16(xsrc + ((size_t)((r >> 2) * NSEQ + bid * 4 + (r & 3))) * 1024 + lane * 16,
                xbuf + r * 1040);
    __syncthreads();

    const f32x4 z4 = {0.f, 0.f, 0.f, 0.f};
    for (int half = 0; half < 2; half++) {
        for (int ss = 0; ss < 25; ss++) {
            int s = half * 25 + ss;
            int cur = s & 1;
            int nxt = cur ^ 1;

            // A-frags: A[m][k] = h[m&3][k] (replicated rows)
            f16x8 afrag[4];
            for (int kq = 0; kq < 4; kq++)
                afrag[kq] = *(const f16x8*)(&hbuf[cur][(col & 3) * 144 + kq * 32 + quad * 8]);

            // x_proj gates from LDS: 4 scalar reads for (seq=quad, hid)
            float xp[4];
            for (int g = 0; g < 4; g++)
                xp[g] = (float)(*(const _Float16*)(xbuf + (ss * 4 + quad) * 1040 +
                               (g * 128 + hid) * 2));

            f32x4 acc[4];
            for (int g = 0; g < 4; g++) {
                acc[g] = z4;
                for (int kq = 0; kq < 4; kq++)
                    acc[g] = __builtin_amdgcn_mfma_f32_16x16x32_f16(afrag[kq], bfrag[g][kq], acc[g], 0, 0, 0);
            }

            // extract element [quad] of each gate vector (C row quad*4+r = seq r)
            float gv[4];
            for (int g = 0; g < 4; g++) {
                float lo = (quad & 1) ? acc[g][1] : acc[g][0];
                float hi = (quad & 1) ? acc[g][3] : acc[g][2];
                gv[g] = (quad & 2) ? hi : lo;
            }

            float ip = gv[0] + xp[0];
            float fp = gv[1] + xp[1];
            float gp = gv[2] + xp[2];
            float op = gv[3] + xp[3];
            float si = __fdividef(1.0f, 1.0f + __expf(-ip));
            float sf = __fdividef(1.0f, 1.0f + __expf(-fp));
            float so = __fdividef(1.0f, 1.0f + __expf(-op));
            float eg = __expf(-2.0f * gp);
            float tg = __fdividef(1.0f - eg, 1.0f + eg);
            cst = sf * cst + si * tg;
            float ec = __expf(-2.0f * cst);
            float tc = __fdividef(1.0f - ec, 1.0f + ec);
            float hv = so * tc;
            _Float16 hv16 = (_Float16)hv;
            hbuf[nxt][quad * 144 + hid] = hv16;
            hst[(s * 4 + quad) * 128 + hid] = hv16;
            __syncthreads();
        }
        if (half == 0) {
            // refill slots 0..24 with steps 25..49 (one-time vmcnt drain)
            for (int r = wave; r < 100; r += 8)
                g2lds16(xsrc + ((size_t)((25 + (r >> 2)) * NSEQ + bid * 4 + (r & 3))) * 1024 + lane * 16,
                        xbuf + r * 1040);
            __syncthreads();
        }
    }

    // coalesced writeout of all 50 steps: 3200 dwordx4
    const u32x4* src = (const u32x4*)hst;
    for (int i = tid; i < 3200; i += 512) {
        int s = i >> 6;            // 64 vec4 per step
        int rem = i & 63;
        int seq = rem >> 4;
        int seg = rem & 15;
        u32x4 v = src[i];
        *(u32x4*)((char*)hseq + ((size_t)(s * NSEQ + bid * 4 + seq)) * 256 + seg * 16) = v;
    }
}

// ---------------- transpose: out[b][hid][s][v] = hseq[s][b*25+v][hid] -------------------
__global__ __launch_bounds__(256) void tr_kernel(const _Float16* __restrict__ hseq,
                                                 float* __restrict__ out) {
    int bid = blockIdx.x;        // 0..799 = b*50+s
    int b = bid / NSEG;
    int s = bid - b * NSEG;
    int tid = threadIdx.x;

    __shared__ _Float16 buf[25 * 130];   // [v][hid], padded 128->130

    const uint32_t* src32 = (const uint32_t*)(hseq + ((size_t)s * NSEQ + b * 25) * HID);
    uint32_t* buf32 = (uint32_t*)buf;
    for (int i = tid; i < 1600; i += 256) {       // 25 rows x 64 dwords, contiguous read
        int v = i >> 6;
        int d = i & 63;
        buf32[v * 65 + d] = src32[i];
    }
    __syncthreads();
    for (int i = tid; i < 3200; i += 256) {
        int hid = i / 25;
        int v = i - hid * 25;
        out[(((size_t)b * 128 + hid) * NSEG + s) * 25 + v] = (float)buf[v * 130 + hid];
    }
}

extern "C" void kernel_launch(void* const* d_in, const int* in_sizes, int n_in,
                              void* d_out, int out_size, void* d_ws, size_t ws_size,
                              hipStream_t stream) {
    const float* x = (const float*)d_in[0];
    const float* Wih = (const float*)d_in[1];
    const float* Whh = (const float*)d_in[2];
    const float* bih = (const float*)d_in[3];
    const float* bhh = (const float*)d_in[4];
    float* out = (float*)d_out;

    char* ws = (char*)d_ws;
    size_t off = 0;
    _Float16* feat = (_Float16*)(ws + off);   off += (size_t)NROW_PAD * KD2 * 2;      // 89.6 MB
    _Float16* xproj2 = (_Float16*)(ws + off); off += (size_t)NSEG * NSEQ * GATES * 2; // 20.5 MB
    _Float16* hseq = (_Float16*)(ws + off);   off += (size_t)NSEG * NSEQ * HID * 2;   // 5.1 MB
    _Float16* wh = (_Float16*)(ws + off);     off += (size_t)512 * KD2 * 2;           // 2.3 MB
    _Float16* whh16 = (_Float16*)(ws + off);  off += (size_t)512 * HID * 2;
    float* bias = (float*)(ws + off);         off += 512 * 4;

    hipLaunchKernelGGL(feat_kernel, dim3(864), dim3(512), 0, stream,
                       x, Wih, Whh, bih, bhh, feat, wh, whh16, bias);
    hipLaunchKernelGGL(gemm_kernel, dim3(1000), dim3(64), 0, stream, feat, wh, bias, xproj2);
    hipLaunchKernelGGL(lstm_kernel, dim3(100), dim3(512), 0, stream, xproj2, whh16, hseq);
    hipLaunchKernelGGL(tr_kernel, dim3(16 * NSEG), dim3(256), 0, stream, hseq, out);
}